// Round 9
// baseline (308.303 us; speedup 1.0000x reference)
//
#include <hip/hip_runtime.h>

// B=2, C=64, D=32, HW=4096; heads=8, hd=8
#define SB   131072          // sites per batch = D*HW
#define CSTR 131072          // channel stride (elements)
#define BSTR 8388608         // batch stride (elements)

using u32x4  = __attribute__((ext_vector_type(4))) unsigned int;
using u32x2  = __attribute__((ext_vector_type(2))) unsigned int;
using bf16x8 = __attribute__((ext_vector_type(8))) short;   // MFMA A/B frag (4 VGPRs)
using f32x4  = __attribute__((ext_vector_type(4))) float;   // MFMA C/D frag
using f32x2  = __attribute__((ext_vector_type(2))) float;   // packed-f32 pair

// Single-instruction bf16 pair pack (RNE). No builtin on gfx950 -> inline asm.
__device__ __forceinline__ unsigned pack2(float a, float b) {
    unsigned r;
    asm("v_cvt_pk_bf16_f32 %0, %1, %2" : "=v"(r) : "v"(a), "v"(b));
    return r;
}
__device__ __forceinline__ float bflo(unsigned u) { return __uint_as_float(u << 16); }
__device__ __forceinline__ float bfhi(unsigned u) { return __uint_as_float(u & 0xffff0000u); }

__device__ __forceinline__ f32x4 mfma16(bf16x8 a, bf16x8 b, f32x4 c) {
    return __builtin_amdgcn_mfma_f32_16x16x32_bf16(a, b, c, 0, 0, 0);
}

// Direct global->LDS (zero-VGPR staging; 16B/lane).
typedef const __attribute__((address_space(1))) void* gptr_t;
typedef __attribute__((address_space(3))) void* lptr_t;
__device__ __forceinline__ void gl_lds16(const float* g, float* l) {
    __builtin_amdgcn_global_load_lds((gptr_t)g, (lptr_t)l, 16, 0, 0);
}

// Load 4 mtiles x 2 ktiles of A-fragments from a row-major fp32 [64][64]
// weight. A-frag layout (16x16x32): lane holds A[m=lane&15][k=quad*8+j].
// Two batches of 8 float4 loads (32 transient VGPRs).
// Round-9: issue weights BEFORE gl_lds -- vmcnt retires in issue order, so
// weight packs (L2-hot, ~200cyc) overlap the HBM staging latency instead of
// serializing after it (r8 lesson: weights-after forces waiting on staging).
#define LOAD_A_FRAGS(A, W, n, qd)                                          \
    _Pragma("unroll")                                                      \
    for (int half = 0; half < 2; ++half) {                                 \
        float4 wr[8];                                                      \
        _Pragma("unroll")                                                  \
        for (int mh = 0; mh < 2; ++mh)                                     \
            _Pragma("unroll")                                              \
            for (int kt = 0; kt < 2; ++kt) {                               \
                const int o = (half * 2 + mh) * 16 + (n);                  \
                const int c = kt * 32 + (qd) * 8;                          \
                wr[(mh * 2 + kt) * 2]     = *(const float4*)&W[o * 64 + c];     \
                wr[(mh * 2 + kt) * 2 + 1] = *(const float4*)&W[o * 64 + c + 4]; \
            }                                                              \
        _Pragma("unroll")                                                  \
        for (int mh = 0; mh < 2; ++mh)                                     \
            _Pragma("unroll")                                              \
            for (int kt = 0; kt < 2; ++kt) {                               \
                union { bf16x8 v; unsigned u[4]; } tw;                     \
                const float4 w0 = wr[(mh * 2 + kt) * 2];                   \
                const float4 w1 = wr[(mh * 2 + kt) * 2 + 1];               \
                tw.u[0] = pack2(w0.x, w0.y);                               \
                tw.u[1] = pack2(w0.z, w0.w);                               \
                tw.u[2] = pack2(w1.x, w1.y);                               \
                tw.u[3] = pack2(w1.z, w1.w);                               \
                A[half * 2 + mh][kt] = tw.v;                               \
            }                                                              \
    }

// B-frag from the wave's fp32 [64ch][32site] LDS tile: 8 channel values at
// one site (stride 128B) per kt, packed to bf16. ~4-way quad conflict, ok.
#define LDS_BFRAG_F32(Bf, col, qd)                                         \
    _Pragma("unroll")                                                      \
    for (int kt = 0; kt < 2; ++kt) {                                       \
        union { bf16x8 v; unsigned u[4]; } tb;                             \
        _Pragma("unroll")                                                  \
        for (int r = 0; r < 4; ++r) {                                      \
            const int c = kt * 32 + (qd) * 8 + 2 * r;                      \
            tb.u[r] = pack2((col)[c * 32], (col)[c * 32 + 32]);            \
        }                                                                  \
        Bf[kt] = tb.v;                                                     \
    }

// ---------------- K1: fused Q | K,V projections (MFMA, gload_lds) ---------
// Round-9: occupancy attack. 4096 blocks x 256 thr (parity: even->Q,
// odd->KV). Wave = 32-site strip; staged tile 64ch x 32site fp32 = 8KB/wave
// -> 32KB/block -> 5 blocks/CU LDS cap (was 64KB -> 2). Three staging
// schemes (r4 gather / r6 reg-batch / r8 gl_lds) all landed ~90-105us at
// 15% occupancy: the limiter is unhidden HBM latency at ~5 waves/CU, not
// issue order. TLP (12+ waves/CU) is the lever.
// Per wave: 8x gl_lds; instr i, lane l -> ch = 8i+(l>>3), sites 4*(l&7)..+3;
// LDS idx i*256+4l == ch*32+site (verified algebra). Wave-private tile ->
// NO __syncthreads.
__global__ __launch_bounds__(256)
void k1_proj(const float* __restrict__ qf, const float* __restrict__ kf,
             const float* __restrict__ Wq, const float* __restrict__ Wk,
             const float* __restrict__ Wv, unsigned* __restrict__ Qs,
             unsigned* __restrict__ Ks, unsigned* __restrict__ Vs)
{
    __shared__ float lsf[8192];   // 4 waves x 2048 floats (8KB each) = 32KB

    const int vbid = blockIdx.x >> 1;
    const int path = blockIdx.x & 1;                       // 0 = Q, 1 = KV
    const int wv   = (int)threadIdx.x >> 6;
    const int wid  = vbid * 4 + wv;                        // 0..8191
    const int lane = threadIdx.x & 63;
    const int qd   = lane >> 4;
    const int n    = lane & 15;
    const int S0   = wid * 32;
    const int b    = S0 >> 17;
    const int tl   = S0 & (SB - 1);
    const int woff = wv * 2048;

    const float* xb = (path == 0 ? qf : kf) + (size_t)b * BSTR;

    if (path == 0) {
        bf16x8 A[4][2];
        LOAD_A_FRAGS(A, Wq, n, qd)          // issued first: packs overlap staging

        // stage 64ch x 32site tile (8 gl_lds, zero VGPR, all in flight)
        {
            const float* gsrc = xb + (size_t)(lane >> 3) * CSTR + tl + (lane & 7) * 4;
            float* ldst = &lsf[woff];
            #pragma unroll
            for (int i = 0; i < 8; ++i)
                gl_lds16(gsrc + (size_t)(8 * i) * CSTR, ldst + i * 256);
        }
        asm volatile("s_waitcnt vmcnt(0)" ::: "memory");
        __builtin_amdgcn_sched_barrier(0);

        #pragma unroll
        for (int t = 0; t < 2; ++t) {
            const int sl   = t * 16 + n;
            const int site = tl + sl;
            const float* col = &lsf[woff + sl];
            bf16x8 Bf[2];
            LDS_BFRAG_F32(Bf, col, qd)
            f32x4 acc[4];
            #pragma unroll
            for (int mt = 0; mt < 4; ++mt) acc[mt] = (f32x4){0.f, 0.f, 0.f, 0.f};
            #pragma unroll
            for (int kt = 0; kt < 2; ++kt)
                #pragma unroll
                for (int mt = 0; mt < 4; ++mt)
                    acc[mt] = mfma16(A[mt][kt], Bf[kt], acc[mt]);
            // lane holds out-ch o = mt*16 + qd*4 + r for its site
            // packed record [b][h][site][8e]; quads 0+1 cover 256B densely
            #pragma unroll
            for (int mt = 0; mt < 4; ++mt) {
                const int h = 2 * mt + (qd >> 1);
                unsigned* dst = Qs + ((unsigned)(b * 8 + h) * SB + site) * 4 + (qd & 1) * 2;
                u32x2 w;
                w.x = pack2(acc[mt][0], acc[mt][1]);
                w.y = pack2(acc[mt][2], acc[mt][3]);
                *(u32x2*)dst = w;
            }
        }
    } else {
        bf16x8 AK[4][2], AV[4][2];
        LOAD_A_FRAGS(AK, Wk, n, qd)
        LOAD_A_FRAGS(AV, Wv, n, qd)

        {
            const float* gsrc = xb + (size_t)(lane >> 3) * CSTR + tl + (lane & 7) * 4;
            float* ldst = &lsf[woff];
            #pragma unroll
            for (int i = 0; i < 8; ++i)
                gl_lds16(gsrc + (size_t)(8 * i) * CSTR, ldst + i * 256);
        }
        asm volatile("s_waitcnt vmcnt(0)" ::: "memory");
        __builtin_amdgcn_sched_barrier(0);

        #pragma unroll
        for (int t = 0; t < 2; ++t) {
            const int sl   = t * 16 + n;
            const int site = tl + sl;
            const float* col = &lsf[woff + sl];
            bf16x8 Bf[2];
            LDS_BFRAG_F32(Bf, col, qd)
            f32x4 aK[4], aV[4];
            #pragma unroll
            for (int mt = 0; mt < 4; ++mt) {
                aK[mt] = (f32x4){0.f, 0.f, 0.f, 0.f};
                aV[mt] = (f32x4){0.f, 0.f, 0.f, 0.f};
            }
            #pragma unroll
            for (int kt = 0; kt < 2; ++kt)
                #pragma unroll
                for (int mt = 0; mt < 4; ++mt) {
                    aK[mt] = mfma16(AK[mt][kt], Bf[kt], aK[mt]);
                    aV[mt] = mfma16(AV[mt][kt], Bf[kt], aV[mt]);
                }
            #pragma unroll
            for (int mt = 0; mt < 4; ++mt) {
                const int h = 2 * mt + (qd >> 1);
                const unsigned off = ((unsigned)(b * 8 + h) * SB + site) * 4 + (qd & 1) * 2;
                u32x2 wk2, wv2;
                wk2.x = pack2(aK[mt][0], aK[mt][1]);
                wk2.y = pack2(aK[mt][2], aK[mt][3]);
                wv2.x = pack2(aV[mt][0], aV[mt][1]);
                wv2.y = pack2(aV[mt][2], aV[mt][3]);
                *(u32x2*)(Ks + off) = wk2;
                *(u32x2*)(Vs + off) = wv2;
            }
        }
    }
}

// ---------------- K2: attention per (pos-window, head) ----------------
// block = 256 thr = 32 pos x 8 dq-threads. K,V tiles in LDS.
// v4 (round-3, VERIFIED 64us, VGPR 44, occ 33%, VALUBusy 71%):
// single-pass fused softmax -- p = exp2(qk); sum += p; cx += p*v.
// No min-waves cap (rounds 1-2: any cap -> scratch spill). Row pairs share
// every LDS read; f32x2 math for v_pk_fma_f32; unroll 4 bounds in-flight
// LDS loads. Max-subtraction dropped (sim*scale ~ N(0,1), exp exact f32).
// NOTE: Cs aliases Qs (pass 0 writes rows 0-15, pass 1 reads rows 16-31;
// disjoint -> no hazard).
__global__ __launch_bounds__(256)
void k2_attn(const u32x4* Qs, const u32x4* __restrict__ Ks,
             const u32x4* __restrict__ Vs, u32x4* Cs)
{
    __shared__ unsigned int kls[4096];  // [d'][pos] 16B each = 16KB
    __shared__ unsigned int vls[4096];  // 16KB

    const int blk = blockIdx.x;          // 2048 blocks
    const int h   = blk & 7;
    const int w   = blk >> 3;            // 0..255
    const int b   = w >> 7;
    const int pos0 = (w & 127) * 32;

    const int tid = threadIdx.x;
    const int pos = tid & 31;
    const int dqt = tid >> 5;            // 0..7

    const int base = (b * 8 + h) * SB;

    #pragma unroll
    for (int i = 0; i < 4; ++i) {
        const int idx = tid + i * 256;       // 0..1023
        const int dp = idx >> 5, pp = idx & 31;
        *(u32x4*)&kls[idx * 4] = Ks[base + dp * 4096 + pos0 + pp];
        *(u32x4*)&vls[idx * 4] = Vs[base + dp * 4096 + pos0 + pp];
    }
    __syncthreads();

    // 8^-0.5 * log2(e): fold softmax scale and exp->exp2 conversion into Q
    const float sc = 0.35355339059327373f * 1.4426950408889634f;

    #pragma unroll 1
    for (int p = 0; p < 2; ++p) {
        const int dq0 = dqt + 16 * p;            // row pair: dq0, dq0+8
        const u32x4 qa = Qs[base + dq0 * 4096 + pos0 + pos];
        const u32x4 qb = Qs[base + (dq0 + 8) * 4096 + pos0 + pos];
        f32x2 q2[8];
        q2[0] = (f32x2){bflo(qa.x) * sc, bflo(qb.x) * sc};
        q2[1] = (f32x2){bfhi(qa.x) * sc, bfhi(qb.x) * sc};
        q2[2] = (f32x2){bflo(qa.y) * sc, bflo(qb.y) * sc};
        q2[3] = (f32x2){bfhi(qa.y) * sc, bfhi(qb.y) * sc};
        q2[4] = (f32x2){bflo(qa.z) * sc, bflo(qb.z) * sc};
        q2[5] = (f32x2){bfhi(qa.z) * sc, bfhi(qb.z) * sc};
        q2[6] = (f32x2){bflo(qa.w) * sc, bflo(qb.w) * sc};
        q2[7] = (f32x2){bfhi(qa.w) * sc, bfhi(qb.w) * sc};

        f32x2 cx[8];
        #pragma unroll
        for (int e = 0; e < 8; ++e) cx[e] = (f32x2){0.f, 0.f};
        f32x2 sum2 = (f32x2){0.f, 0.f};

        #pragma unroll 4
        for (int dp = 0; dp < 32; ++dp) {
            const u32x4 kk = *(const u32x4*)&kls[(dp * 32 + pos) * 4];
            const u32x4 vv = *(const u32x4*)&vls[(dp * 32 + pos) * 4];
            // two shorter dependency chains, then join
            f32x2 accA = q2[0] * bflo(kk.x);
            f32x2 accB = q2[1] * bfhi(kk.x);
            accA += q2[2] * bflo(kk.y);
            accB += q2[3] * bfhi(kk.y);
            accA += q2[4] * bflo(kk.z);
            accB += q2[5] * bfhi(kk.z);
            accA += q2[6] * bflo(kk.w);
            accB += q2[7] * bfhi(kk.w);
            const f32x2 acc = accA + accB;
            f32x2 ex;
            ex.x = exp2f(acc.x);       // p = exp(sim*scale), unnormalized
            ex.y = exp2f(acc.y);
            sum2 += ex;
            cx[0] += ex * bflo(vv.x);
            cx[1] += ex * bfhi(vv.x);
            cx[2] += ex * bflo(vv.y);
            cx[3] += ex * bfhi(vv.y);
            cx[4] += ex * bflo(vv.z);
            cx[5] += ex * bfhi(vv.z);
            cx[6] += ex * bflo(vv.w);
            cx[7] += ex * bfhi(vv.w);
        }

        const f32x2 inv2 = (f32x2){1.0f / sum2.x, 1.0f / sum2.y};
        #pragma unroll
        for (int e = 0; e < 8; ++e) cx[e] *= inv2;

        u32x4 pa, pb;
        pa.x = pack2(cx[0].x, cx[1].x); pa.y = pack2(cx[2].x, cx[3].x);
        pa.z = pack2(cx[4].x, cx[5].x); pa.w = pack2(cx[6].x, cx[7].x);
        pb.x = pack2(cx[0].y, cx[1].y); pb.y = pack2(cx[2].y, cx[3].y);
        pb.z = pack2(cx[4].y, cx[5].y); pb.w = pack2(cx[6].y, cx[7].y);
        Cs[base + dq0 * 4096 + pos0 + pos] = pa;
        Cs[base + (dq0 + 8) * 4096 + pos0 + pos] = pb;
    }
}

// ---------------- K3: Wo projection (MFMA) ----------------
// B-frag = one dwordx4 ctx record, already bf16 in e-order. No conversion.
// Ctx frags batched (8 x 16B, 32 VGPRs) before the 2-batch weight load.
__global__ __launch_bounds__(256)
void k3_out(const u32x4* __restrict__ Cs, const float* __restrict__ Wo,
            float* __restrict__ out)
{
    const int wid  = (blockIdx.x * 256 + threadIdx.x) >> 6;
    const int lane = threadIdx.x & 63;
    const int qd   = lane >> 4;
    const int n    = lane & 15;
    const int S0   = wid * 64;
    const int b    = S0 >> 17;
    const int tl   = S0 & (SB - 1);

    // batch the 8 cold ctx-frag loads first (k = kt*32+qd*8+j -> h=kt*4+qd)
    bf16x8 Bf[4][2];
    #pragma unroll
    for (int t = 0; t < 4; ++t) {
        const int site = tl + t * 16 + n;
        #pragma unroll
        for (int kt = 0; kt < 2; ++kt)
            Bf[t][kt] = *(const bf16x8*)(Cs + (unsigned)(b * 8 + kt * 4 + qd) * SB + site);
    }

    bf16x8 A[4][2];
    LOAD_A_FRAGS(A, Wo, n, qd)

    #pragma unroll
    for (int t = 0; t < 4; ++t) {
        const int site = tl + t * 16 + n;
        f32x4 acc[4];
        #pragma unroll
        for (int mt = 0; mt < 4; ++mt) acc[mt] = (f32x4){0.f, 0.f, 0.f, 0.f};
        #pragma unroll
        for (int kt = 0; kt < 2; ++kt)
            #pragma unroll
            for (int mt = 0; mt < 4; ++mt)
                acc[mt] = mfma16(A[mt][kt], Bf[t][kt], acc[mt]);
        #pragma unroll
        for (int mt = 0; mt < 4; ++mt)
            #pragma unroll
            for (int r = 0; r < 4; ++r)
                out[(size_t)b * BSTR + (size_t)(mt * 16 + qd * 4 + r) * CSTR + site]
                    = acc[mt][r];
    }
}

extern "C" void kernel_launch(void* const* d_in, const int* in_sizes, int n_in,
                              void* d_out, int out_size, void* d_ws, size_t ws_size,
                              hipStream_t stream) {
    const float* qf = (const float*)d_in[0];
    const float* kf = (const float*)d_in[1];
    const float* Wq = (const float*)d_in[2];
    const float* Wk = (const float*)d_in[3];
    const float* Wv = (const float*)d_in[4];
    const float* Wo = (const float*)d_in[5];
    float* out = (float*)d_out;

    // scratch layout (bf16 records, 33.55MB each):
    //   ws:    Q (later overwritten in-place by ctx) | V     -> 67.1MB used
    //   d_out: K (33.55MB <= 64MB)  -> overwritten by K3's fp32 out (K dead)
    unsigned* Qs = (unsigned*)d_ws;
    unsigned* Vs = (unsigned*)((char*)d_ws + (size_t)33554432);
    unsigned* Ks = (unsigned*)d_out;

    hipLaunchKernelGGL(k1_proj, dim3(4096), dim3(256), 0, stream,
                       qf, kf, Wq, Wk, Wv, Qs, Ks, Vs);
    hipLaunchKernelGGL(k2_attn, dim3(2048), dim3(256), 0, stream,
                       (const u32x4*)Qs, (const u32x4*)Ks, (const u32x4*)Vs,
                       (u32x4*)Qs);
    hipLaunchKernelGGL(k3_out, dim3(1024), dim3(256), 0, stream,
                       (const u32x4*)Qs, Wo, out);
}

// Round 10
// 279.952 us; speedup vs baseline: 1.1013x; 1.1013x over previous
//
#include <hip/hip_runtime.h>

// B=2, C=64, D=32, HW=4096; heads=8, hd=8
#define SB   131072          // sites per batch = D*HW
#define CSTR 131072          // channel stride (elements)
#define BSTR 8388608         // batch stride (elements)

using u32x4  = __attribute__((ext_vector_type(4))) unsigned int;
using u32x2  = __attribute__((ext_vector_type(2))) unsigned int;
using bf16x8 = __attribute__((ext_vector_type(8))) short;   // MFMA A/B frag (4 VGPRs)
using f32x4  = __attribute__((ext_vector_type(4))) float;   // MFMA C/D frag
using f32x2  = __attribute__((ext_vector_type(2))) float;   // packed-f32 pair

// Single-instruction bf16 pair pack (RNE). No builtin on gfx950 -> inline asm.
__device__ __forceinline__ unsigned pack2(float a, float b) {
    unsigned r;
    asm("v_cvt_pk_bf16_f32 %0, %1, %2" : "=v"(r) : "v"(a), "v"(b));
    return r;
}
__device__ __forceinline__ float bflo(unsigned u) { return __uint_as_float(u << 16); }
__device__ __forceinline__ float bfhi(unsigned u) { return __uint_as_float(u & 0xffff0000u); }

__device__ __forceinline__ f32x4 mfma16(bf16x8 a, bf16x8 b, f32x4 c) {
    return __builtin_amdgcn_mfma_f32_16x16x32_bf16(a, b, c, 0, 0, 0);
}

// Direct global->LDS (zero-VGPR staging; 16B/lane).
typedef const __attribute__((address_space(1))) void* gptr_t;
typedef __attribute__((address_space(3))) void* lptr_t;
__device__ __forceinline__ void gl_lds16(const float* g, float* l) {
    __builtin_amdgcn_global_load_lds((gptr_t)g, (lptr_t)l, 16, 0, 0);
}

// Load 4 mtiles x 2 ktiles of A-fragments from a row-major fp32 [64][64]
// weight. Two batches of 8 float4 loads (32 transient VGPRs).
#define LOAD_A_FRAGS(A, W, n, qd)                                          \
    _Pragma("unroll")                                                      \
    for (int half = 0; half < 2; ++half) {                                 \
        float4 wr[8];                                                      \
        _Pragma("unroll")                                                  \
        for (int mh = 0; mh < 2; ++mh)                                     \
            _Pragma("unroll")                                              \
            for (int kt = 0; kt < 2; ++kt) {                               \
                const int o = (half * 2 + mh) * 16 + (n);                  \
                const int c = kt * 32 + (qd) * 8;                          \
                wr[(mh * 2 + kt) * 2]     = *(const float4*)&W[o * 64 + c];     \
                wr[(mh * 2 + kt) * 2 + 1] = *(const float4*)&W[o * 64 + c + 4]; \
            }                                                              \
        _Pragma("unroll")                                                  \
        for (int mh = 0; mh < 2; ++mh)                                     \
            _Pragma("unroll")                                              \
            for (int kt = 0; kt < 2; ++kt) {                               \
                union { bf16x8 v; unsigned u[4]; } tw;                     \
                const float4 w0 = wr[(mh * 2 + kt) * 2];                   \
                const float4 w1 = wr[(mh * 2 + kt) * 2 + 1];               \
                tw.u[0] = pack2(w0.x, w0.y);                               \
                tw.u[1] = pack2(w0.z, w0.w);                               \
                tw.u[2] = pack2(w1.x, w1.y);                               \
                tw.u[3] = pack2(w1.z, w1.w);                               \
                A[half * 2 + mh][kt] = tw.v;                               \
            }                                                              \
    }

// B-frag from a fp32 [64ch][32site] LDS tile: 8 ch at one site per kt.
#define LDS_BFRAG_F32(Bf, col, qd)                                         \
    _Pragma("unroll")                                                      \
    for (int kt = 0; kt < 2; ++kt) {                                       \
        union { bf16x8 v; unsigned u[4]; } tb;                             \
        _Pragma("unroll")                                                  \
        for (int r = 0; r < 4; ++r) {                                      \
            const int c = kt * 32 + (qd) * 8 + 2 * r;                      \
            tb.u[r] = pack2((col)[c * 32], (col)[c * 32 + 32]);            \
        }                                                                  \
        Bf[kt] = tb.v;                                                     \
    }

// ---------------- K1: fused Q | K,V projections (persistent + pipelined) --
// Round-10 insight: every one-shot variant (r4 gather, r6 reg-batch, r8/r9
// gl_lds) landed 90-111us with occupancy PINNED at 15-16% regardless of
// VGPR/LDS -- residency is not resource-capped; the exposed HBM round trip
// per short-lived wave is the cost. Fix: persistent waves LOOP over 8
// strips with double-buffered gl_lds prefetch and COUNTED vmcnt (prefetch
// loads always the oldest outstanding ops; stores stay in flight).
// 512 blocks x 256 thr; even->Q, odd->KV. Wave = 32-site strip/iter,
// dbuf 2x8KB/wave -> 64KB/block. Weights loaded once (8x amortized).
// LDS: instr i, lane l -> ch=8i+(l>>3), site 4*(l&7)..+3; idx i*256+4l ==
// ch*32+site (r9-verified algebra). Wave-private -> no __syncthreads.
__global__ __launch_bounds__(256)
void k1_proj(const float* __restrict__ qf, const float* __restrict__ kf,
             const float* __restrict__ Wq, const float* __restrict__ Wk,
             const float* __restrict__ Wv, unsigned* __restrict__ Qs,
             unsigned* __restrict__ Ks, unsigned* __restrict__ Vs)
{
    __shared__ float lsf[16384];   // 4 waves x (2 x 2048 floats) = 64KB

    const int vbid = blockIdx.x >> 1;                      // 0..255
    const int path = blockIdx.x & 1;                       // 0 = Q, 1 = KV
    const int wv   = (int)threadIdx.x >> 6;
    const int wid0 = vbid * 4 + wv;                        // 0..1023
    const int lane = threadIdx.x & 63;
    const int qd   = lane >> 4;
    const int n    = lane & 15;
    float* buf0 = &lsf[wv * 4096];
    float* buf1 = buf0 + 2048;

    const float* xb0 = (path == 0) ? qf : kf;

    // per-strip staging: 8x gl_lds of 1KB into dst
    auto prefetch = [&](int strip, float* dst) {
        const int S0 = strip * 32;
        const float* gsrc = xb0 + (size_t)(S0 >> 17) * BSTR
                          + (size_t)(lane >> 3) * CSTR + (S0 & (SB - 1))
                          + (lane & 7) * 4;
        #pragma unroll
        for (int i = 0; i < 8; ++i)
            gl_lds16(gsrc + (size_t)(8 * i) * CSTR, dst + i * 256);
    };

    if (path == 0) {
        bf16x8 A[4][2];
        LOAD_A_FRAGS(A, Wq, n, qd)

        auto compute = [&](const float* buf, int strip) {
            const int S0 = strip * 32;
            const int b  = S0 >> 17;
            const int tl = S0 & (SB - 1);
            #pragma unroll
            for (int t = 0; t < 2; ++t) {
                const int sl   = t * 16 + n;
                const int site = tl + sl;
                bf16x8 Bf[2];
                LDS_BFRAG_F32(Bf, buf + sl, qd)
                f32x4 acc[4];
                #pragma unroll
                for (int mt = 0; mt < 4; ++mt) acc[mt] = (f32x4){0.f, 0.f, 0.f, 0.f};
                #pragma unroll
                for (int kt = 0; kt < 2; ++kt)
                    #pragma unroll
                    for (int mt = 0; mt < 4; ++mt)
                        acc[mt] = mfma16(A[mt][kt], Bf[kt], acc[mt]);
                #pragma unroll
                for (int mt = 0; mt < 4; ++mt) {
                    const int h = 2 * mt + (qd >> 1);
                    unsigned* dst = Qs + ((unsigned)(b * 8 + h) * SB + site) * 4 + (qd & 1) * 2;
                    u32x2 w;
                    w.x = pack2(acc[mt][0], acc[mt][1]);
                    w.y = pack2(acc[mt][2], acc[mt][3]);
                    *(u32x2*)dst = w;      // 8 stores per strip (2t x 4mt)
                }
            }
        };

        prefetch(wid0, buf0);
        asm volatile("s_waitcnt vmcnt(0)" ::: "memory");
        __builtin_amdgcn_sched_barrier(0);
        #pragma unroll 1
        for (int it = 0; it < 7; ++it) {
            float* nxt = (it & 1) ? buf0 : buf1;
            prefetch(wid0 + (it + 1) * 1024, nxt);      // 8 loads (oldest)
            compute((it & 1) ? buf1 : buf0, wid0 + it * 1024);  // 8 stores
            // <=8 outstanding: the 8 youngest are this iter's stores ->
            // the prefetch loads (older) have retired; stores stay in flight
            asm volatile("s_waitcnt vmcnt(8)" ::: "memory");
            __builtin_amdgcn_sched_barrier(0);
        }
        compute(buf1, wid0 + 7 * 1024);
    } else {
        bf16x8 AK[4][2], AV[4][2];
        LOAD_A_FRAGS(AK, Wk, n, qd)
        LOAD_A_FRAGS(AV, Wv, n, qd)

        auto computekv = [&](const float* buf, int strip) {
            const int S0 = strip * 32;
            const int b  = S0 >> 17;
            const int tl = S0 & (SB - 1);
            #pragma unroll
            for (int t = 0; t < 2; ++t) {
                const int sl   = t * 16 + n;
                const int site = tl + sl;
                bf16x8 Bf[2];
                LDS_BFRAG_F32(Bf, buf + sl, qd)
                f32x4 aK[4], aV[4];
                #pragma unroll
                for (int mt = 0; mt < 4; ++mt) {
                    aK[mt] = (f32x4){0.f, 0.f, 0.f, 0.f};
                    aV[mt] = (f32x4){0.f, 0.f, 0.f, 0.f};
                }
                #pragma unroll
                for (int kt = 0; kt < 2; ++kt)
                    #pragma unroll
                    for (int mt = 0; mt < 4; ++mt) {
                        aK[mt] = mfma16(AK[mt][kt], Bf[kt], aK[mt]);
                        aV[mt] = mfma16(AV[mt][kt], Bf[kt], aV[mt]);
                    }
                #pragma unroll
                for (int mt = 0; mt < 4; ++mt) {
                    const int h = 2 * mt + (qd >> 1);
                    const unsigned off = ((unsigned)(b * 8 + h) * SB + site) * 4 + (qd & 1) * 2;
                    u32x2 wk2, wv2;
                    wk2.x = pack2(aK[mt][0], aK[mt][1]);
                    wk2.y = pack2(aK[mt][2], aK[mt][3]);
                    wv2.x = pack2(aV[mt][0], aV[mt][1]);
                    wv2.y = pack2(aV[mt][2], aV[mt][3]);
                    *(u32x2*)(Ks + off) = wk2;
                    *(u32x2*)(Vs + off) = wv2;   // 16 stores per strip
                }
            }
        };

        prefetch(wid0, buf0);
        asm volatile("s_waitcnt vmcnt(0)" ::: "memory");
        __builtin_amdgcn_sched_barrier(0);
        #pragma unroll 1
        for (int it = 0; it < 7; ++it) {
            float* nxt = (it & 1) ? buf0 : buf1;
            prefetch(wid0 + (it + 1) * 1024, nxt);        // 8 loads (oldest)
            computekv((it & 1) ? buf1 : buf0, wid0 + it * 1024); // 16 stores
            asm volatile("s_waitcnt vmcnt(16)" ::: "memory");
            __builtin_amdgcn_sched_barrier(0);
        }
        computekv(buf1, wid0 + 7 * 1024);
    }
}

// ---------------- K2: attention per (pos-window, head) ----------------
// block = 256 thr = 32 pos x 8 dq-threads. K,V tiles in LDS.
// v4 (round-3, VERIFIED 64us, VGPR 44, occ 33%, VALUBusy 71%):
// single-pass fused softmax -- p = exp2(qk); sum += p; cx += p*v.
// No min-waves cap (rounds 1-2: any cap -> scratch spill). Row pairs share
// every LDS read; f32x2 math for v_pk_fma_f32; unroll 4 bounds in-flight
// LDS loads. Max-subtraction dropped (sim*scale ~ N(0,1), exp exact f32).
// NOTE: Cs aliases Qs (pass 0 writes rows 0-15, pass 1 reads rows 16-31;
// disjoint -> no hazard).
__global__ __launch_bounds__(256)
void k2_attn(const u32x4* Qs, const u32x4* __restrict__ Ks,
             const u32x4* __restrict__ Vs, u32x4* Cs)
{
    __shared__ unsigned int kls[4096];  // [d'][pos] 16B each = 16KB
    __shared__ unsigned int vls[4096];  // 16KB

    const int blk = blockIdx.x;          // 2048 blocks
    const int h   = blk & 7;
    const int w   = blk >> 3;            // 0..255
    const int b   = w >> 7;
    const int pos0 = (w & 127) * 32;

    const int tid = threadIdx.x;
    const int pos = tid & 31;
    const int dqt = tid >> 5;            // 0..7

    const int base = (b * 8 + h) * SB;

    #pragma unroll
    for (int i = 0; i < 4; ++i) {
        const int idx = tid + i * 256;       // 0..1023
        const int dp = idx >> 5, pp = idx & 31;
        *(u32x4*)&kls[idx * 4] = Ks[base + dp * 4096 + pos0 + pp];
        *(u32x4*)&vls[idx * 4] = Vs[base + dp * 4096 + pos0 + pp];
    }
    __syncthreads();

    // 8^-0.5 * log2(e): fold softmax scale and exp->exp2 conversion into Q
    const float sc = 0.35355339059327373f * 1.4426950408889634f;

    #pragma unroll 1
    for (int p = 0; p < 2; ++p) {
        const int dq0 = dqt + 16 * p;            // row pair: dq0, dq0+8
        const u32x4 qa = Qs[base + dq0 * 4096 + pos0 + pos];
        const u32x4 qb = Qs[base + (dq0 + 8) * 4096 + pos0 + pos];
        f32x2 q2[8];
        q2[0] = (f32x2){bflo(qa.x) * sc, bflo(qb.x) * sc};
        q2[1] = (f32x2){bfhi(qa.x) * sc, bfhi(qb.x) * sc};
        q2[2] = (f32x2){bflo(qa.y) * sc, bflo(qb.y) * sc};
        q2[3] = (f32x2){bfhi(qa.y) * sc, bfhi(qb.y) * sc};
        q2[4] = (f32x2){bflo(qa.z) * sc, bflo(qb.z) * sc};
        q2[5] = (f32x2){bfhi(qa.z) * sc, bfhi(qb.z) * sc};
        q2[6] = (f32x2){bflo(qa.w) * sc, bflo(qb.w) * sc};
        q2[7] = (f32x2){bfhi(qa.w) * sc, bfhi(qb.w) * sc};

        f32x2 cx[8];
        #pragma unroll
        for (int e = 0; e < 8; ++e) cx[e] = (f32x2){0.f, 0.f};
        f32x2 sum2 = (f32x2){0.f, 0.f};

        #pragma unroll 4
        for (int dp = 0; dp < 32; ++dp) {
            const u32x4 kk = *(const u32x4*)&kls[(dp * 32 + pos) * 4];
            const u32x4 vv = *(const u32x4*)&vls[(dp * 32 + pos) * 4];
            // two shorter dependency chains, then join
            f32x2 accA = q2[0] * bflo(kk.x);
            f32x2 accB = q2[1] * bfhi(kk.x);
            accA += q2[2] * bflo(kk.y);
            accB += q2[3] * bfhi(kk.y);
            accA += q2[4] * bflo(kk.z);
            accB += q2[5] * bfhi(kk.z);
            accA += q2[6] * bflo(kk.w);
            accB += q2[7] * bfhi(kk.w);
            const f32x2 acc = accA + accB;
            f32x2 ex;
            ex.x = exp2f(acc.x);       // p = exp(sim*scale), unnormalized
            ex.y = exp2f(acc.y);
            sum2 += ex;
            cx[0] += ex * bflo(vv.x);
            cx[1] += ex * bfhi(vv.x);
            cx[2] += ex * bflo(vv.y);
            cx[3] += ex * bfhi(vv.y);
            cx[4] += ex * bflo(vv.z);
            cx[5] += ex * bfhi(vv.z);
            cx[6] += ex * bflo(vv.w);
            cx[7] += ex * bfhi(vv.w);
        }

        const f32x2 inv2 = (f32x2){1.0f / sum2.x, 1.0f / sum2.y};
        #pragma unroll
        for (int e = 0; e < 8; ++e) cx[e] *= inv2;

        u32x4 pa, pb;
        pa.x = pack2(cx[0].x, cx[1].x); pa.y = pack2(cx[2].x, cx[3].x);
        pa.z = pack2(cx[4].x, cx[5].x); pa.w = pack2(cx[6].x, cx[7].x);
        pb.x = pack2(cx[0].y, cx[1].y); pb.y = pack2(cx[2].y, cx[3].y);
        pb.z = pack2(cx[4].y, cx[5].y); pb.w = pack2(cx[6].y, cx[7].y);
        Cs[base + dq0 * 4096 + pos0 + pos] = pa;
        Cs[base + (dq0 + 8) * 4096 + pos0 + pos] = pb;
    }
}

// ---------------- K3: Wo projection (MFMA) ----------------
// B-frag = one dwordx4 ctx record, already bf16 in e-order. No conversion.
// Ctx frags batched (8 x 16B, 32 VGPRs) before the 2-batch weight load.
__global__ __launch_bounds__(256)
void k3_out(const u32x4* __restrict__ Cs, const float* __restrict__ Wo,
            float* __restrict__ out)
{
    const int wid  = (blockIdx.x * 256 + threadIdx.x) >> 6;
    const int lane = threadIdx.x & 63;
    const int qd   = lane >> 4;
    const int n    = lane & 15;
    const int S0   = wid * 64;
    const int b    = S0 >> 17;
    const int tl   = S0 & (SB - 1);

    // batch the 8 cold ctx-frag loads first (k = kt*32+qd*8+j -> h=kt*4+qd)
    bf16x8 Bf[4][2];
    #pragma unroll
    for (int t = 0; t < 4; ++t) {
        const int site = tl + t * 16 + n;
        #pragma unroll
        for (int kt = 0; kt < 2; ++kt)
            Bf[t][kt] = *(const bf16x8*)(Cs + (unsigned)(b * 8 + kt * 4 + qd) * SB + site);
    }

    bf16x8 A[4][2];
    LOAD_A_FRAGS(A, Wo, n, qd)

    #pragma unroll
    for (int t = 0; t < 4; ++t) {
        const int site = tl + t * 16 + n;
        f32x4 acc[4];
        #pragma unroll
        for (int mt = 0; mt < 4; ++mt) acc[mt] = (f32x4){0.f, 0.f, 0.f, 0.f};
        #pragma unroll
        for (int kt = 0; kt < 2; ++kt)
            #pragma unroll
            for (int mt = 0; mt < 4; ++mt)
                acc[mt] = mfma16(A[mt][kt], Bf[t][kt], acc[mt]);
        #pragma unroll
        for (int mt = 0; mt < 4; ++mt)
            #pragma unroll
            for (int r = 0; r < 4; ++r)
                out[(size_t)b * BSTR + (size_t)(mt * 16 + qd * 4 + r) * CSTR + site]
                    = acc[mt][r];
    }
}

extern "C" void kernel_launch(void* const* d_in, const int* in_sizes, int n_in,
                              void* d_out, int out_size, void* d_ws, size_t ws_size,
                              hipStream_t stream) {
    const float* qf = (const float*)d_in[0];
    const float* kf = (const float*)d_in[1];
    const float* Wq = (const float*)d_in[2];
    const float* Wk = (const float*)d_in[3];
    const float* Wv = (const float*)d_in[4];
    const float* Wo = (const float*)d_in[5];
    float* out = (float*)d_out;

    // scratch layout (bf16 records, 33.55MB each):
    //   ws:    Q (later overwritten in-place by ctx) | V     -> 67.1MB used
    //   d_out: K (33.55MB <= 64MB)  -> overwritten by K3's fp32 out (K dead)
    unsigned* Qs = (unsigned*)d_ws;
    unsigned* Vs = (unsigned*)((char*)d_ws + (size_t)33554432);
    unsigned* Ks = (unsigned*)d_out;

    hipLaunchKernelGGL(k1_proj, dim3(512), dim3(256), 0, stream,
                       qf, kf, Wq, Wk, Wv, Qs, Ks, Vs);
    hipLaunchKernelGGL(k2_attn, dim3(2048), dim3(256), 0, stream,
                       (const u32x4*)Qs, (const u32x4*)Ks, (const u32x4*)Vs,
                       (u32x4*)Qs);
    hipLaunchKernelGGL(k3_out, dim3(1024), dim3(256), 0, stream,
                       (const u32x4*)Qs, Wo, out);
}